// Round 13
// baseline (470.364 us; speedup 1.0000x reference)
//
#include <hip/hip_runtime.h>
#include <stdint.h>

// Problem constants (fixed by the reference)
#define NV    8192   // variables
#define NC    4096   // checks
#define DC    6      // edges per check
#define DV    3      // edges per variable
#define NE    24576  // edges
#define NITER 5
#define BATCH 2048

// ---------------------------------------------------------------------------
// Setup 1: per-var edge lists (sorted ascending so the np.add.at association
// and slot ranks are deterministic).
// ---------------------------------------------------------------------------

__global__ void build_v2e(const int* __restrict__ cols, int* __restrict__ cnt,
                          unsigned short* __restrict__ v2e_tmp) {
  int e = blockIdx.x * blockDim.x + threadIdx.x;
  if (e >= NE) return;
  int v = cols[e];
  int s = atomicAdd(&cnt[v], 1);
  v2e_tmp[v * DV + s] = (unsigned short)e;
}

// Setup 2: per-edge slot codes, contiguous per check: cslot[e] = k*NV + v,
// where k = rank of edge e among its var's ascending edges. (e = c*6 + j.)
__global__ void invert_slots(const unsigned short* __restrict__ v2e_tmp,
                             unsigned short* __restrict__ cslot) {
  int v = blockIdx.x * blockDim.x + threadIdx.x;
  if (v >= NV) return;
  int a = v2e_tmp[v * 3 + 0];
  int b = v2e_tmp[v * 3 + 1];
  int c = v2e_tmp[v * 3 + 2];
  int t;
  if (a > b) { t = a; a = b; b = t; }
  if (b > c) { t = b; b = c; c = t; }
  if (a > b) { t = a; a = b; b = t; }
  cslot[a] = (unsigned short)(0 * NV + v);
  cslot[b] = (unsigned short)(1 * NV + v);
  cslot[c] = (unsigned short)(2 * NV + v);
}

// ---------------------------------------------------------------------------
// Setup 3: EXACT bank schedule via bipartite edge coloring (Kempe chains),
// REGISTER-RESIDENT rewrite of R12 (R12 proved the coloring's decode win but
// spent ~200us on dependent byte-wise LDS state; here the hot state is in
// registers as bitmasks, only the rare chain walk touches LDS).
// 256 independent problems, one per (decode-wave wv, r-block rr, quarter qq):
// 16 checks x 6 edges, banks = slot & 31, colors = rows 0..5.
// One thread per problem, no atomics: DETERMINISTIC.
// Any per-check color permutation is BIT-EXACT for the decoder (check update
// is order-symmetric); a per-check validity check falls back to identity.
// ---------------------------------------------------------------------------

__global__ __launch_bounds__(64) void kempe_schedule(
    const unsigned short* __restrict__ cslot, unsigned int* __restrict__ slotp) {
  __shared__ unsigned short SL[64][96];    // edge -> slot code
  __shared__ unsigned char  EB[64][96];    // edge -> bank
  __shared__ unsigned char  LE[64][96];    // lane*6+color -> edge (0xFF none)
  __shared__ unsigned char  BE[64][192];   // bank*6+color -> rep edge
  __shared__ unsigned char  CH[64][48];    // chain scratch

  const int t = threadIdx.x;
  const int pid = blockIdx.x * 64 + t;     // 0..255
  const int wv = pid >> 4, rr = (pid >> 2) & 3, qq = pid & 3;

  // Register bitmask state.
  unsigned long long u0 = 0, u1 = 0, u2 = 0, u3 = 0;  // (bank,color) used
  unsigned long long d0 = 0, d1 = 0, d2 = 0, d3 = 0;  // (bank,color) count>=2
  unsigned long long lmLo = 0, lmHi = 0;              // lane color masks (6b)

  auto getu = [&](int b) -> int {
    unsigned long long w = (b >> 3) == 0 ? u0 : (b >> 3) == 1 ? u1 : (b >> 3) == 2 ? u2 : u3;
    return (int)(w >> ((b & 7) * 6)) & 63;
  };
  auto getd = [&](int b) -> int {
    unsigned long long w = (b >> 3) == 0 ? d0 : (b >> 3) == 1 ? d1 : (b >> 3) == 2 ? d2 : d3;
    return (int)(w >> ((b & 7) * 6)) & 63;
  };
  auto setu = [&](int b, int c) {
    unsigned long long bit = 1ULL << ((b & 7) * 6 + c); int w = b >> 3;
    if (w == 0) u0 |= bit; else if (w == 1) u1 |= bit; else if (w == 2) u2 |= bit; else u3 |= bit;
  };
  auto clru = [&](int b, int c) {
    unsigned long long bit = 1ULL << ((b & 7) * 6 + c); int w = b >> 3;
    if (w == 0) u0 &= ~bit; else if (w == 1) u1 &= ~bit; else if (w == 2) u2 &= ~bit; else u3 &= ~bit;
  };
  auto setd = [&](int b, int c) {
    unsigned long long bit = 1ULL << ((b & 7) * 6 + c); int w = b >> 3;
    if (w == 0) d0 |= bit; else if (w == 1) d1 |= bit; else if (w == 2) d2 |= bit; else d3 |= bit;
  };
  auto getl = [&](int l) -> int {
    return (int)((l < 10 ? (lmLo >> (l * 6)) : (lmHi >> ((l - 10) * 6))) & 63);
  };
  auto setl = [&](int l, int c) {
    if (l < 10) lmLo |= 1ULL << (l * 6 + c); else lmHi |= 1ULL << ((l - 10) * 6 + c);
  };
  auto clrl = [&](int l, int c) {
    if (l < 10) lmLo &= ~(1ULL << (l * 6 + c)); else lmHi &= ~(1ULL << ((l - 10) * 6 + c));
  };

  for (int i = 0; i < 96; ++i) LE[t][i] = 0xFF;
  for (int i = 0; i < 192; ++i) BE[t][i] = 0xFF;

  const unsigned int* cs32 = (const unsigned int*)cslot;
  for (int i = 0; i < 16; ++i) {
    int chk = rr * 1024 + wv * 64 + qq * 16 + i;
    unsigned int a0 = cs32[chk * 3 + 0];
    unsigned int a1 = cs32[chk * 3 + 1];
    unsigned int a2 = cs32[chk * 3 + 2];
    unsigned short s0 = (unsigned short)(a0 & 0xffffu), s1 = (unsigned short)(a0 >> 16);
    unsigned short s2 = (unsigned short)(a1 & 0xffffu), s3 = (unsigned short)(a1 >> 16);
    unsigned short s4 = (unsigned short)(a2 & 0xffffu), s5 = (unsigned short)(a2 >> 16);
    unsigned short sv[6] = {s0, s1, s2, s3, s4, s5};

#pragma unroll
    for (int k = 0; k < 6; ++k) {
      const int e = i * 6 + k;
      const int b = sv[k] & 31;
      SL[t][e] = sv[k];
      EB[t][e] = (unsigned char)b;

      int freeL = (~getl(i)) & 63;
      int usedB = getu(b);
      int cand = freeL & (~usedB) & 63;
      int c = -1;
      if (cand) {
        c = __builtin_ctz((unsigned)cand);
      } else {
        int a = __builtin_ctz((unsigned)freeL);
        int fB = (~usedB) & 63;
        int dupB = getd(b);
        if (fB && ((usedB >> a) & 1) && !((dupB >> a) & 1)) {
          int cB = __builtin_ctz((unsigned)fB);
          // ---- walk a/cB alternating path from bank b (LDS only here) -----
          int n = 0, ok = 1;
          int cur = BE[t][b * 6 + a];
          while (1) {
            if (n >= 48) { ok = 0; break; }
            CH[t][n++] = (unsigned char)cur;            // even pos: colored a
            int lc = (cur * 171) >> 10;                 // cur / 6
            int nxt = LE[t][lc * 6 + cB];
            if (nxt == 0xFF) break;                     // ends at lane
            if (n >= 48) { ok = 0; break; }
            CH[t][n++] = (unsigned char)nxt;            // odd pos: colored cB
            int bn = EB[t][nxt];
            int dB2 = getd(bn);
            if ((dB2 >> cB) & 1) { ok = 0; break; }     // sticky rep: abort
            if (!((getu(bn) >> a) & 1)) break;          // ends at bank
            if ((dB2 >> a) & 1) { ok = 0; break; }
            cur = BE[t][bn * 6 + a];
          }
          if (ok) {
            // ---- flip: pass 1 clear old colors, pass 2 set swapped --------
            for (int m = 0; m < n; ++m) {
              int e2 = CH[t][m]; int f = (m & 1) ? cB : a;
              int l2 = (e2 * 171) >> 10; int b2 = EB[t][e2];
              if (LE[t][l2 * 6 + f] == e2) LE[t][l2 * 6 + f] = 0xFF;
              clrl(l2, f);
              clru(b2, f);
              if (BE[t][b2 * 6 + f] == e2) BE[t][b2 * 6 + f] = 0xFF;
            }
            for (int m = 0; m < n; ++m) {
              int e2 = CH[t][m]; int tt = (m & 1) ? a : cB;
              int l2 = (e2 * 171) >> 10; int b2 = EB[t][e2];
              LE[t][l2 * 6 + tt] = (unsigned char)e2;
              setl(l2, tt);
              if ((getu(b2) >> tt) & 1) { setd(b2, tt); }
              else { setu(b2, tt); BE[t][b2 * 6 + tt] = (unsigned char)e2; }
            }
            if (!((getl(i) >> a) & 1)) c = a;            // lemma holds
          }
        }
        if (c < 0) {
          // sticky fallback (recompute: the flip may have freed something)
          freeL = (~getl(i)) & 63;
          usedB = getu(b);
          cand = freeL & (~usedB) & 63;
          if (cand) c = __builtin_ctz((unsigned)cand);
          else {
            int dupB = getd(b);
            int once = freeL & usedB & (~dupB) & 63;
            c = once ? __builtin_ctz((unsigned)once)
                     : __builtin_ctz((unsigned)freeL);
          }
        }
      }
      // place e at color c
      setl(i, c);
      LE[t][i * 6 + c] = (unsigned char)e;
      if ((getu(b) >> c) & 1) { setd(b, c); }
      else { setu(b, c); BE[t][b * 6 + c] = (unsigned char)e; }
    }
  }

  // ---- emit (identity fallback if a lane's coloring is somehow invalid) ---
  for (int i = 0; i < 16; ++i) {
    unsigned short pm[6];
    if (getl(i) == 63) {
#pragma unroll
      for (int c2 = 0; c2 < 6; ++c2) pm[c2] = SL[t][LE[t][i * 6 + c2]];
    } else {
#pragma unroll
      for (int c2 = 0; c2 < 6; ++c2) pm[c2] = SL[t][i * 6 + c2];
    }
    int cpos = rr * 1024 + wv * 64 + qq * 16 + i;
    slotp[0 * NC + cpos] = (unsigned int)pm[0] | ((unsigned int)pm[1] << 16);
    slotp[1 * NC + cpos] = (unsigned int)pm[2] | ((unsigned int)pm[3] << 16);
    slotp[2 * NC + cpos] = (unsigned int)pm[4] | ((unsigned int)pm[5] << 16);
  }
}

// ---------------------------------------------------------------------------
// Fused decoder (R10-verbatim): one workgroup per batch element.
// LDS: 3 c2v planes (var-major, 96 KB) + 1 vl plane (32 KB) = 128 KB.
// c2v lives in the owning check-thread's REGISTERS across iterations.
// ---------------------------------------------------------------------------

__global__ __launch_bounds__(1024, 4) void decode_kernel(
    const float* __restrict__ ch, const float* __restrict__ wts,
    const unsigned int* __restrict__ slotp, float* __restrict__ out) {
  __shared__ float s_msg[NE];   // c2v planes, 96 KB
  __shared__ float s_vl[NV];    // var LLR plane, 32 KB

  const int tid = threadIdx.x;
  const int b = blockIdx.x;
  const float* chrow = ch + (size_t)b * NV;
  const float4* ch4 = (const float4*)chrow;

  float4 chreg[2];
  chreg[0] = ch4[tid];           // vars 4*tid .. 4*tid+3
  chreg[1] = ch4[1024 + tid];    // vars 4096+4*tid ..

  float w[NITER];
#pragma unroll
  for (int i = 0; i < NITER; ++i) w[i] = wts[i];

  // Preload slot indices (writes) and masked var indices (vl reads).
  int idx[4][6];
  int vidx[4][6];
#pragma unroll
  for (int r = 0; r < 4; ++r) {
    int c = tid + r * 1024;
    unsigned int p0 = slotp[c];
    unsigned int p1 = slotp[NC + c];
    unsigned int p2 = slotp[2 * NC + c];
    idx[r][0] = (int)(p0 & 0xFFFFu); idx[r][1] = (int)(p0 >> 16);
    idx[r][2] = (int)(p1 & 0xFFFFu); idx[r][3] = (int)(p1 >> 16);
    idx[r][4] = (int)(p2 & 0xFFFFu); idx[r][5] = (int)(p2 >> 16);
#pragma unroll
    for (int j = 0; j < 6; ++j) vidx[r][j] = idx[r][j] & (NV - 1);
  }

  // c2v for this thread's 4 checks, resident in registers across iterations.
  float creg[4][6];
#pragma unroll
  for (int r = 0; r < 4; ++r)
#pragma unroll
    for (int j = 0; j < 6; ++j) creg[r][j] = 0.0f;

  float4* m0 = (float4*)&s_msg[0];
  float4* m1 = (float4*)&s_msg[NV];
  float4* m2 = (float4*)&s_msg[2 * NV];
  float4* vl4 = (float4*)s_vl;

  // ---- init: vl = ch (it0 v2c = vl - 0 = ch) ------------------------------
#pragma unroll
  for (int p = 0; p < 2; ++p) vl4[p * 1024 + tid] = chreg[p];
  __syncthreads();

  for (int it = 0; it < NITER; ++it) {
    const float wi = w[it];

    // ---- Phase B: hoist ALL 24 vl reads (independent, pipelined) ----------
    float tv[4][6];
#pragma unroll
    for (int r = 0; r < 4; ++r)
#pragma unroll
      for (int j = 0; j < 6; ++j) tv[r][j] = s_vl[vidx[r][j]];

    // ---- Phase B compute + writes -----------------------------------------
#pragma unroll
    for (int r = 0; r < 4; ++r) {
      unsigned int u[6];
      float av[6];
      unsigned int xs = 0u;
#pragma unroll
      for (int j = 0; j < 6; ++j) {
        float t = tv[r][j] - creg[r][j];
        unsigned int uu = __float_as_uint(t);
        u[j] = uu;
        xs ^= uu;
        av[j] = __uint_as_float(uu & 0x7FFFFFFFu);
      }
      // 2-min tree: exact, order-independent (min3/med3/max)
      float m1a = fminf(fminf(av[0], av[1]), av[2]);
      float m1b = fminf(fminf(av[3], av[4]), av[5]);
      float meda = __builtin_amdgcn_fmed3f(av[0], av[1], av[2]);
      float medb = __builtin_amdgcn_fmed3f(av[3], av[4], av[5]);
      float m1v = fminf(m1a, m1b);
      float m2v = fminf(fminf(meda, medb), fmaxf(m1a, m1b));
      const bool anyz = (m1v == 0.0f);
      const float m1w = m1v * wi;
      const float m2w = m2v * wi;
#pragma unroll
      for (int j = 0; j < 6; ++j) {
        float mag = (av[j] == m1v) ? m2w : m1w;  // ties: m2v==m1v, matches ref
        unsigned int s = (xs ^ u[j]) & 0x80000000u;
        float o = __uint_as_float(__float_as_uint(mag) ^ s);
        if (anyz) o = 0.0f;
        creg[r][j] = o;
        s_msg[idx[r][j]] = o;
      }
    }
    __syncthreads();

    // ---- Phase A: vl = ch + ((c0+c1)+c2), one wide write ------------------
    if (it < NITER - 1) {
#pragma unroll
      for (int p = 0; p < 2; ++p) {
        int i4 = p * 1024 + tid;
        float4 c0 = m0[i4], c1 = m1[i4], c2 = m2[i4];
        float4 cr = chreg[p];
        float4 vl;
        vl.x = cr.x + ((c0.x + c1.x) + c2.x);   // np.add.at association
        vl.y = cr.y + ((c0.y + c1.y) + c2.y);
        vl.z = cr.z + ((c0.z + c1.z) + c2.z);
        vl.w = cr.w + ((c0.w + c1.w) + c2.w);
        vl4[i4] = vl;
      }
      __syncthreads();
    }
  }

  // ---- Final: out = ch + ((c0+c1)+c2), float4 stores ----------------------
  float4* orow4 = (float4*)(out + (size_t)b * NV);
#pragma unroll
  for (int p = 0; p < 2; ++p) {
    int i4 = p * 1024 + tid;
    float4 c0 = m0[i4], c1 = m1[i4], c2 = m2[i4];
    float4 cr = chreg[p];
    float4 o;
    o.x = cr.x + ((c0.x + c1.x) + c2.x);
    o.y = cr.y + ((c0.y + c1.y) + c2.y);
    o.z = cr.z + ((c0.z + c1.z) + c2.z);
    o.w = cr.w + ((c0.w + c1.w) + c2.w);
    orow4[i4] = o;
  }
}

// ---------------------------------------------------------------------------

extern "C" void kernel_launch(void* const* d_in, const int* in_sizes, int n_in,
                              void* d_out, int out_size, void* d_ws, size_t ws_size,
                              hipStream_t stream) {
  (void)in_sizes; (void)n_in; (void)out_size; (void)ws_size;

  const float* ch   = (const float*)d_in[0];   // [BATCH, NV] f32
  const float* wts  = (const float*)d_in[1];   // [NITER, 1] f32
  const int*  Hcols = (const int*)d_in[3];     // [NE] i32
  float* out = (float*)d_out;

  char* ws = (char*)d_ws;
  int*            cnt     = (int*)(ws + 0);                  // 32768 B
  unsigned short* v2e_tmp = (unsigned short*)(ws + 32768);   // 49152 B
  unsigned short* cslot   = (unsigned short*)(ws + 81920);   // 49152 B
  unsigned int*   slotp   = (unsigned int*)(ws + 131072);    // 49152 B
  // total ws use: 180224 B

  hipMemsetAsync(cnt, 0, NV * sizeof(int), stream);
  build_v2e<<<(NE + 255) / 256, 256, 0, stream>>>(Hcols, cnt, v2e_tmp);
  invert_slots<<<(NV + 255) / 256, 256, 0, stream>>>(v2e_tmp, cslot);
  kempe_schedule<<<4, 64, 0, stream>>>(cslot, slotp);

  decode_kernel<<<BATCH, 1024, 0, stream>>>(ch, wts, slotp, out);
}

// Round 14
// 214.971 us; speedup vs baseline: 2.1880x; 2.1880x over previous
//
#include <hip/hip_runtime.h>
#include <stdint.h>

// Problem constants (fixed by the reference)
#define NV    8192   // variables
#define NC    4096   // checks
#define DC    6      // edges per check
#define DV    3      // edges per variable
#define NE    24576  // edges
#define NITER 5
#define BATCH 2048

// ---------------------------------------------------------------------------
// Setup 1: per-var edge lists (sorted ascending so the np.add.at association
// and slot ranks are deterministic).
// ---------------------------------------------------------------------------

__global__ void build_v2e(const int* __restrict__ cols, int* __restrict__ cnt,
                          unsigned short* __restrict__ v2e_tmp) {
  int e = blockIdx.x * blockDim.x + threadIdx.x;
  if (e >= NE) return;
  int v = cols[e];
  int s = atomicAdd(&cnt[v], 1);
  v2e_tmp[v * DV + s] = (unsigned short)e;
}

// Setup 2: per-edge slot codes, contiguous per check: cslot[e] = k*NV + v,
// where k = rank of edge e among its var's ascending edges. (e = c*6 + j.)
__global__ void invert_slots(const unsigned short* __restrict__ v2e_tmp,
                             unsigned short* __restrict__ cslot) {
  int v = blockIdx.x * blockDim.x + threadIdx.x;
  if (v >= NV) return;
  int a = v2e_tmp[v * 3 + 0];
  int b = v2e_tmp[v * 3 + 1];
  int c = v2e_tmp[v * 3 + 2];
  int t;
  if (a > b) { t = a; a = b; b = t; }
  if (b > c) { t = b; b = c; c = t; }
  if (a > b) { t = a; a = b; b = t; }
  cslot[a] = (unsigned short)(0 * NV + v);
  cslot[b] = (unsigned short)(1 * NV + v);
  cslot[c] = (unsigned short)(2 * NV + v);
}

// ---------------------------------------------------------------------------
// Setup 3: EXACT bank schedule via bipartite edge coloring (Kempe chains).
// R13 post-mortem: per-lane problems serialize under 64-way divergence
// (363us = 64 x serial). Fix: ONE PROBLEM PER WORKGROUP (256 blocks); lanes
// parallelize init/load/emit, lane 0 alone runs the serial core with
// register-bitmask state — no divergence, 256 CUs concurrent, ~5us wall.
// Problem (wave wv, r-block rr, quarter qq): 16 checks x 6 edges,
// banks = slot & 31, colors = rows 0..5. Deterministic (single-thread core).
// Any per-check color permutation is BIT-EXACT for the decoder (check update
// is order-symmetric); identity fallback if a lane's coloring is invalid.
// ---------------------------------------------------------------------------

__global__ __launch_bounds__(64) void kempe_schedule(
    const unsigned short* __restrict__ cslot, unsigned int* __restrict__ slotp) {
  __shared__ unsigned short SL[96];    // edge -> slot code
  __shared__ unsigned char  EB[96];    // edge -> bank
  __shared__ unsigned char  LE[96];    // lane*6+color -> edge (0xFF none)
  __shared__ unsigned char  BE[192];   // bank*6+color -> rep edge
  __shared__ unsigned char  CH[48];    // chain scratch (lane 0 only)
  __shared__ unsigned int   validMask; // 16-bit per-check coloring-valid

  const int t = threadIdx.x;
  const int pid = blockIdx.x;          // 0..255
  const int wv = pid >> 4, rr = (pid >> 2) & 3, qq = pid & 3;

  // ---- parallel init + load ----------------------------------------------
  { // 96 edges: 2 strided passes over 64 lanes
    for (int i = t; i < 96; i += 64) LE[i] = 0xFF;
    for (int i = t; i < 192; i += 64) BE[i] = 0xFF;
    if (t < 16) {
      const unsigned int* cs32 = (const unsigned int*)cslot;
      int chk = rr * 1024 + wv * 64 + qq * 16 + t;
      unsigned int a0 = cs32[chk * 3 + 0];
      unsigned int a1 = cs32[chk * 3 + 1];
      unsigned int a2 = cs32[chk * 3 + 2];
      unsigned short sv[6];
      sv[0] = (unsigned short)(a0 & 0xffffu); sv[1] = (unsigned short)(a0 >> 16);
      sv[2] = (unsigned short)(a1 & 0xffffu); sv[3] = (unsigned short)(a1 >> 16);
      sv[4] = (unsigned short)(a2 & 0xffffu); sv[5] = (unsigned short)(a2 >> 16);
#pragma unroll
      for (int k = 0; k < 6; ++k) {
        SL[t * 6 + k] = sv[k];
        EB[t * 6 + k] = (unsigned char)(sv[k] & 31);
      }
    }
  }
  __syncthreads();

  // ---- serial Kempe core on lane 0 (register-bitmask state) ---------------
  if (t == 0) {
    unsigned long long u0 = 0, u1 = 0, u2 = 0, u3 = 0;  // (bank,color) used
    unsigned long long d0 = 0, d1 = 0, d2 = 0, d3 = 0;  // (bank,color) >=2
    unsigned long long lmLo = 0, lmHi = 0;              // lane color masks

    auto getu = [&](int b) -> int {
      unsigned long long w = (b >> 3) == 0 ? u0 : (b >> 3) == 1 ? u1 : (b >> 3) == 2 ? u2 : u3;
      return (int)(w >> ((b & 7) * 6)) & 63;
    };
    auto getd = [&](int b) -> int {
      unsigned long long w = (b >> 3) == 0 ? d0 : (b >> 3) == 1 ? d1 : (b >> 3) == 2 ? d2 : d3;
      return (int)(w >> ((b & 7) * 6)) & 63;
    };
    auto setu = [&](int b, int c) {
      unsigned long long bit = 1ULL << ((b & 7) * 6 + c); int w = b >> 3;
      if (w == 0) u0 |= bit; else if (w == 1) u1 |= bit; else if (w == 2) u2 |= bit; else u3 |= bit;
    };
    auto clru = [&](int b, int c) {
      unsigned long long bit = 1ULL << ((b & 7) * 6 + c); int w = b >> 3;
      if (w == 0) u0 &= ~bit; else if (w == 1) u1 &= ~bit; else if (w == 2) u2 &= ~bit; else u3 &= ~bit;
    };
    auto setd = [&](int b, int c) {
      unsigned long long bit = 1ULL << ((b & 7) * 6 + c); int w = b >> 3;
      if (w == 0) d0 |= bit; else if (w == 1) d1 |= bit; else if (w == 2) d2 |= bit; else d3 |= bit;
    };
    auto getl = [&](int l) -> int {
      return (int)((l < 10 ? (lmLo >> (l * 6)) : (lmHi >> ((l - 10) * 6))) & 63);
    };
    auto setl = [&](int l, int c) {
      if (l < 10) lmLo |= 1ULL << (l * 6 + c); else lmHi |= 1ULL << ((l - 10) * 6 + c);
    };
    auto clrl = [&](int l, int c) {
      if (l < 10) lmLo &= ~(1ULL << (l * 6 + c)); else lmHi &= ~(1ULL << ((l - 10) * 6 + c));
    };

    for (int i = 0; i < 16; ++i) {
      for (int k = 0; k < 6; ++k) {
        const int e = i * 6 + k;
        const int b = EB[e];

        int freeL = (~getl(i)) & 63;
        int usedB = getu(b);
        int cand = freeL & (~usedB) & 63;
        int c = -1;
        if (cand) {
          c = __builtin_ctz((unsigned)cand);
        } else {
          int a = __builtin_ctz((unsigned)freeL);
          int fB = (~usedB) & 63;
          int dupB = getd(b);
          if (fB && ((usedB >> a) & 1) && !((dupB >> a) & 1)) {
            int cB = __builtin_ctz((unsigned)fB);
            // ---- walk a/cB alternating path from bank b -------------------
            int n = 0, ok = 1;
            int cur = BE[b * 6 + a];
            while (1) {
              if (n >= 48) { ok = 0; break; }
              CH[n++] = (unsigned char)cur;             // even pos: colored a
              int lc = (cur * 171) >> 10;               // cur / 6
              int nxt = LE[lc * 6 + cB];
              if (nxt == 0xFF) break;                   // ends at lane
              if (n >= 48) { ok = 0; break; }
              CH[n++] = (unsigned char)nxt;             // odd pos: colored cB
              int bn = EB[nxt];
              int dB2 = getd(bn);
              if ((dB2 >> cB) & 1) { ok = 0; break; }   // sticky rep: abort
              if (!((getu(bn) >> a) & 1)) break;        // ends at bank
              if ((dB2 >> a) & 1) { ok = 0; break; }
              cur = BE[bn * 6 + a];
            }
            if (ok) {
              // ---- flip: pass 1 clear old, pass 2 set swapped -------------
              for (int m = 0; m < n; ++m) {
                int e2 = CH[m]; int f = (m & 1) ? cB : a;
                int l2 = (e2 * 171) >> 10; int b2 = EB[e2];
                if (LE[l2 * 6 + f] == e2) LE[l2 * 6 + f] = 0xFF;
                clrl(l2, f);
                clru(b2, f);
                if (BE[b2 * 6 + f] == e2) BE[b2 * 6 + f] = 0xFF;
              }
              for (int m = 0; m < n; ++m) {
                int e2 = CH[m]; int tt = (m & 1) ? a : cB;
                int l2 = (e2 * 171) >> 10; int b2 = EB[e2];
                LE[l2 * 6 + tt] = (unsigned char)e2;
                setl(l2, tt);
                if ((getu(b2) >> tt) & 1) { setd(b2, tt); }
                else { setu(b2, tt); BE[b2 * 6 + tt] = (unsigned char)e2; }
              }
              if (!((getl(i) >> a) & 1)) c = a;          // lemma holds
            }
          }
          if (c < 0) {
            // sticky fallback (recompute: the flip may have freed something)
            freeL = (~getl(i)) & 63;
            usedB = getu(b);
            cand = freeL & (~usedB) & 63;
            if (cand) c = __builtin_ctz((unsigned)cand);
            else {
              int dupB2 = getd(b);
              int once = freeL & usedB & (~dupB2) & 63;
              c = once ? __builtin_ctz((unsigned)once)
                       : __builtin_ctz((unsigned)freeL);
            }
          }
        }
        // place e at color c
        setl(i, c);
        LE[i * 6 + c] = (unsigned char)e;
        if ((getu(b) >> c) & 1) { setd(b, c); }
        else { setu(b, c); BE[b * 6 + c] = (unsigned char)e; }
      }
    }

    unsigned int vm = 0;
    for (int i = 0; i < 16; ++i) if (getl(i) == 63) vm |= (1u << i);
    validMask = vm;
  }
  __syncthreads();

  // ---- parallel emit (threads 0..15, one check each) ----------------------
  if (t < 16) {
    unsigned short pm[6];
    if ((validMask >> t) & 1) {
#pragma unroll
      for (int c2 = 0; c2 < 6; ++c2) pm[c2] = SL[LE[t * 6 + c2]];
    } else {
#pragma unroll
      for (int c2 = 0; c2 < 6; ++c2) pm[c2] = SL[t * 6 + c2];
    }
    int cpos = rr * 1024 + wv * 64 + qq * 16 + t;
    slotp[0 * NC + cpos] = (unsigned int)pm[0] | ((unsigned int)pm[1] << 16);
    slotp[1 * NC + cpos] = (unsigned int)pm[2] | ((unsigned int)pm[3] << 16);
    slotp[2 * NC + cpos] = (unsigned int)pm[4] | ((unsigned int)pm[5] << 16);
  }
}

// ---------------------------------------------------------------------------
// Fused decoder (R10-verbatim): one workgroup per batch element.
// LDS: 3 c2v planes (var-major, 96 KB) + 1 vl plane (32 KB) = 128 KB.
// c2v lives in the owning check-thread's REGISTERS across iterations.
// ---------------------------------------------------------------------------

__global__ __launch_bounds__(1024, 4) void decode_kernel(
    const float* __restrict__ ch, const float* __restrict__ wts,
    const unsigned int* __restrict__ slotp, float* __restrict__ out) {
  __shared__ float s_msg[NE];   // c2v planes, 96 KB
  __shared__ float s_vl[NV];    // var LLR plane, 32 KB

  const int tid = threadIdx.x;
  const int b = blockIdx.x;
  const float* chrow = ch + (size_t)b * NV;
  const float4* ch4 = (const float4*)chrow;

  float4 chreg[2];
  chreg[0] = ch4[tid];           // vars 4*tid .. 4*tid+3
  chreg[1] = ch4[1024 + tid];    // vars 4096+4*tid ..

  float w[NITER];
#pragma unroll
  for (int i = 0; i < NITER; ++i) w[i] = wts[i];

  // Preload slot indices (writes) and masked var indices (vl reads).
  int idx[4][6];
  int vidx[4][6];
#pragma unroll
  for (int r = 0; r < 4; ++r) {
    int c = tid + r * 1024;
    unsigned int p0 = slotp[c];
    unsigned int p1 = slotp[NC + c];
    unsigned int p2 = slotp[2 * NC + c];
    idx[r][0] = (int)(p0 & 0xFFFFu); idx[r][1] = (int)(p0 >> 16);
    idx[r][2] = (int)(p1 & 0xFFFFu); idx[r][3] = (int)(p1 >> 16);
    idx[r][4] = (int)(p2 & 0xFFFFu); idx[r][5] = (int)(p2 >> 16);
#pragma unroll
    for (int j = 0; j < 6; ++j) vidx[r][j] = idx[r][j] & (NV - 1);
  }

  // c2v for this thread's 4 checks, resident in registers across iterations.
  float creg[4][6];
#pragma unroll
  for (int r = 0; r < 4; ++r)
#pragma unroll
    for (int j = 0; j < 6; ++j) creg[r][j] = 0.0f;

  float4* m0 = (float4*)&s_msg[0];
  float4* m1 = (float4*)&s_msg[NV];
  float4* m2 = (float4*)&s_msg[2 * NV];
  float4* vl4 = (float4*)s_vl;

  // ---- init: vl = ch (it0 v2c = vl - 0 = ch) ------------------------------
#pragma unroll
  for (int p = 0; p < 2; ++p) vl4[p * 1024 + tid] = chreg[p];
  __syncthreads();

  for (int it = 0; it < NITER; ++it) {
    const float wi = w[it];

    // ---- Phase B: hoist ALL 24 vl reads (independent, pipelined) ----------
    float tv[4][6];
#pragma unroll
    for (int r = 0; r < 4; ++r)
#pragma unroll
      for (int j = 0; j < 6; ++j) tv[r][j] = s_vl[vidx[r][j]];

    // ---- Phase B compute + writes -----------------------------------------
#pragma unroll
    for (int r = 0; r < 4; ++r) {
      unsigned int u[6];
      float av[6];
      unsigned int xs = 0u;
#pragma unroll
      for (int j = 0; j < 6; ++j) {
        float t = tv[r][j] - creg[r][j];
        unsigned int uu = __float_as_uint(t);
        u[j] = uu;
        xs ^= uu;
        av[j] = __uint_as_float(uu & 0x7FFFFFFFu);
      }
      // 2-min tree: exact, order-independent (min3/med3/max)
      float m1a = fminf(fminf(av[0], av[1]), av[2]);
      float m1b = fminf(fminf(av[3], av[4]), av[5]);
      float meda = __builtin_amdgcn_fmed3f(av[0], av[1], av[2]);
      float medb = __builtin_amdgcn_fmed3f(av[3], av[4], av[5]);
      float m1v = fminf(m1a, m1b);
      float m2v = fminf(fminf(meda, medb), fmaxf(m1a, m1b));
      const bool anyz = (m1v == 0.0f);
      const float m1w = m1v * wi;
      const float m2w = m2v * wi;
#pragma unroll
      for (int j = 0; j < 6; ++j) {
        float mag = (av[j] == m1v) ? m2w : m1w;  // ties: m2v==m1v, matches ref
        unsigned int s = (xs ^ u[j]) & 0x80000000u;
        float o = __uint_as_float(__float_as_uint(mag) ^ s);
        if (anyz) o = 0.0f;
        creg[r][j] = o;
        s_msg[idx[r][j]] = o;
      }
    }
    __syncthreads();

    // ---- Phase A: vl = ch + ((c0+c1)+c2), one wide write ------------------
    if (it < NITER - 1) {
#pragma unroll
      for (int p = 0; p < 2; ++p) {
        int i4 = p * 1024 + tid;
        float4 c0 = m0[i4], c1 = m1[i4], c2 = m2[i4];
        float4 cr = chreg[p];
        float4 vl;
        vl.x = cr.x + ((c0.x + c1.x) + c2.x);   // np.add.at association
        vl.y = cr.y + ((c0.y + c1.y) + c2.y);
        vl.z = cr.z + ((c0.z + c1.z) + c2.z);
        vl.w = cr.w + ((c0.w + c1.w) + c2.w);
        vl4[i4] = vl;
      }
      __syncthreads();
    }
  }

  // ---- Final: out = ch + ((c0+c1)+c2), float4 stores ----------------------
  float4* orow4 = (float4*)(out + (size_t)b * NV);
#pragma unroll
  for (int p = 0; p < 2; ++p) {
    int i4 = p * 1024 + tid;
    float4 c0 = m0[i4], c1 = m1[i4], c2 = m2[i4];
    float4 cr = chreg[p];
    float4 o;
    o.x = cr.x + ((c0.x + c1.x) + c2.x);
    o.y = cr.y + ((c0.y + c1.y) + c2.y);
    o.z = cr.z + ((c0.z + c1.z) + c2.z);
    o.w = cr.w + ((c0.w + c1.w) + c2.w);
    orow4[i4] = o;
  }
}

// ---------------------------------------------------------------------------

extern "C" void kernel_launch(void* const* d_in, const int* in_sizes, int n_in,
                              void* d_out, int out_size, void* d_ws, size_t ws_size,
                              hipStream_t stream) {
  (void)in_sizes; (void)n_in; (void)out_size; (void)ws_size;

  const float* ch   = (const float*)d_in[0];   // [BATCH, NV] f32
  const float* wts  = (const float*)d_in[1];   // [NITER, 1] f32
  const int*  Hcols = (const int*)d_in[3];     // [NE] i32
  float* out = (float*)d_out;

  char* ws = (char*)d_ws;
  int*            cnt     = (int*)(ws + 0);                  // 32768 B
  unsigned short* v2e_tmp = (unsigned short*)(ws + 32768);   // 49152 B
  unsigned short* cslot   = (unsigned short*)(ws + 81920);   // 49152 B
  unsigned int*   slotp   = (unsigned int*)(ws + 131072);    // 49152 B
  // total ws use: 180224 B

  hipMemsetAsync(cnt, 0, NV * sizeof(int), stream);
  build_v2e<<<(NE + 255) / 256, 256, 0, stream>>>(Hcols, cnt, v2e_tmp);
  invert_slots<<<(NV + 255) / 256, 256, 0, stream>>>(v2e_tmp, cslot);
  kempe_schedule<<<256, 64, 0, stream>>>(cslot, slotp);

  decode_kernel<<<BATCH, 1024, 0, stream>>>(ch, wts, slotp, out);
}

// Round 15
// 147.236 us; speedup vs baseline: 3.1946x; 1.4600x over previous
//
#include <hip/hip_runtime.h>
#include <stdint.h>

// Problem constants (fixed by the reference)
#define NV    8192   // variables
#define NC    4096   // checks
#define DC    6      // edges per check
#define DV    3      // edges per variable
#define NE    24576  // edges
#define NITER 5
#define BATCH 2048

// ---------------------------------------------------------------------------
// Setup A (fused, single block): build per-var edge lists (LDS atomics, LDS
// v2e), sort each var's 3 edges ascending (deterministic; fixes the np.add.at
// association and slot ranks), emit per-edge slot codes to global:
// cslot[e] = k*NV + v, k = rank of e among var v's ascending edges.
// Replaces memset + build_v2e + invert_slots (2 launches + a stream memset).
// ---------------------------------------------------------------------------

__global__ __launch_bounds__(1024) void build_all(const int* __restrict__ cols,
                                                  unsigned short* __restrict__ cslot) {
  __shared__ int cnt[NV];                  // 32 KB
  __shared__ unsigned short v2e[NV * 3];   // 48 KB

  const int t = threadIdx.x;
  for (int i = t; i < NV; i += 1024) cnt[i] = 0;
  __syncthreads();

#pragma unroll
  for (int k = 0; k < 24; ++k) {
    int e = t + k * 1024;
    int v = cols[e];
    int s = atomicAdd(&cnt[v], 1);
    v2e[v * 3 + s] = (unsigned short)e;
  }
  __syncthreads();

#pragma unroll
  for (int i = 0; i < 8; ++i) {
    int v = t + i * 1024;
    int a = v2e[v * 3 + 0];
    int b = v2e[v * 3 + 1];
    int c = v2e[v * 3 + 2];
    int tt;
    if (a > b) { tt = a; a = b; b = tt; }
    if (b > c) { tt = b; b = c; c = tt; }
    if (a > b) { tt = a; a = b; b = tt; }
    cslot[a] = (unsigned short)(0 * NV + v);
    cslot[b] = (unsigned short)(1 * NV + v);
    cslot[c] = (unsigned short)(2 * NV + v);
  }
}

// ---------------------------------------------------------------------------
// Setup B: QUARTER-granular greedy bank schedule (R8-verbatim; ties the exact
// Kempe coloring within the unschedulable conflict floor at ~1/20th the cost).
// Lanes of the same 16-lane quarter hitting the same bank serialize; objective
// per row j and quarter q: <=1 lane per bank (bank = var & 31).
// Any per-check edge permutation is BIT-EXACT for the decoder (check update
// is order-symmetric), so scheduler races never affect d_out.
// ---------------------------------------------------------------------------

__device__ __forceinline__ int qc(int n) { return (n > 1) ? (n - 1) : 0; }

__global__ __launch_bounds__(64) void greedy_schedule(
    const unsigned short* __restrict__ cslot, unsigned int* __restrict__ slotp) {
  __shared__ unsigned short sl[64][6];
  __shared__ unsigned char perm[64][6];
  __shared__ int qhist[4][32];    // quarter, bank: candidate contention
  __shared__ int cnt[6][4][32];   // row, quarter, bank

  const int l = threadIdx.x;
  const int q = l >> 4;
  const int c = blockIdx.x * 64 + l;

  const unsigned int* cs32 = (const unsigned int*)cslot;
  unsigned int a0 = cs32[c * 3 + 0];
  unsigned int a1 = cs32[c * 3 + 1];
  unsigned int a2 = cs32[c * 3 + 2];
  sl[l][0] = (unsigned short)(a0 & 0xffffu); sl[l][1] = (unsigned short)(a0 >> 16);
  sl[l][2] = (unsigned short)(a1 & 0xffffu); sl[l][3] = (unsigned short)(a1 >> 16);
  sl[l][4] = (unsigned short)(a2 & 0xffffu); sl[l][5] = (unsigned short)(a2 >> 16);

  int bank[6];
#pragma unroll
  for (int k = 0; k < 6; ++k) bank[k] = sl[l][k] & 31;

  for (int t = l; t < 128; t += 64) ((int*)qhist)[t] = 0;
  for (int t = l; t < 768; t += 64) ((int*)cnt)[t] = 0;
  __syncthreads();

#pragma unroll
  for (int k = 0; k < 6; ++k) atomicAdd(&qhist[q][bank[k]], 1);
  __syncthreads();

  // ---- per-lane candidate order: contention descending (15-CE network) ----
  int key[6];
#pragma unroll
  for (int k = 0; k < 6; ++k) key[k] = (qhist[q][bank[k]] << 3) | k;
#pragma unroll
  for (int i = 0; i < 5; ++i) {
#pragma unroll
    for (int j2 = 0; j2 < 5 - i; ++j2) {
      if (key[j2] < key[j2 + 1]) {
        int t = key[j2]; key[j2] = key[j2 + 1]; key[j2 + 1] = t;
      }
    }
  }

  // ---- Stage 1: hardest-first strict auction, relaxed fallback ------------
  unsigned int used = 0;
  for (int j = 0; j < 6; ++j) {
    int placed = -1;
    for (int s = 0; s < 6; ++s) {
      int k = key[s] & 7;
      if (used & (1u << k)) continue;
      int bk = bank[k];
      if (cnt[j][q][bk] == 0) {
        if (atomicAdd(&cnt[j][q][bk], 1) == 0) { placed = k; break; }
        atomicSub(&cnt[j][q][bk], 1);
      }
    }
    if (placed < 0) {                    // relaxed: min-count unused candidate
      int bc = 1 << 30;
      for (int k = 0; k < 6; ++k) {
        if (used & (1u << k)) continue;
        int cc = cnt[j][q][bank[k]];
        if (cc < bc) { bc = cc; placed = k; }
      }
      atomicAdd(&cnt[j][q][bank[placed]], 1);
    }
    used |= (1u << placed);
    perm[l][j] = (unsigned char)placed;
    __syncthreads();
  }

  // ---- Stage 2: ONE quarter-cost swap-improvement pass --------------------
  for (int j1 = 0; j1 < 6; ++j1) {
    for (int j2 = j1 + 1; j2 < 6; ++j2) {
      int k1 = perm[l][j1], k2 = perm[l][j2];
      int b1 = bank[k1], b2 = bank[k2];
      if (b1 != b2) {
        int c11 = cnt[j1][q][b1], c12 = cnt[j1][q][b2];
        int c21 = cnt[j2][q][b1], c22 = cnt[j2][q][b2];
        int dOld = qc(c11) + qc(c12) + qc(c21) + qc(c22);
        int dNew = qc(c11 - 1) + qc(c12 + 1) + qc(c21 + 1) + qc(c22 - 1);
        if (dNew < dOld) {
          atomicSub(&cnt[j1][q][b1], 1); atomicAdd(&cnt[j1][q][b2], 1);
          atomicSub(&cnt[j2][q][b2], 1); atomicAdd(&cnt[j2][q][b1], 1);
          perm[l][j1] = (unsigned char)k2; perm[l][j2] = (unsigned char)k1;
        }
      }
      __syncthreads();
    }
  }

  unsigned short pm[6];
#pragma unroll
  for (int j = 0; j < 6; ++j) pm[j] = sl[l][perm[l][j]];
  slotp[0 * NC + c] = (unsigned int)pm[0] | ((unsigned int)pm[1] << 16);
  slotp[1 * NC + c] = (unsigned int)pm[2] | ((unsigned int)pm[3] << 16);
  slotp[2 * NC + c] = (unsigned int)pm[4] | ((unsigned int)pm[5] << 16);
}

// ---------------------------------------------------------------------------
// Fused decoder (R10-verbatim): one workgroup per batch element.
// LDS: 3 c2v planes (var-major, 96 KB) + 1 vl plane (32 KB) = 128 KB.
// c2v lives in the owning check-thread's REGISTERS across iterations.
// ---------------------------------------------------------------------------

__global__ __launch_bounds__(1024, 4) void decode_kernel(
    const float* __restrict__ ch, const float* __restrict__ wts,
    const unsigned int* __restrict__ slotp, float* __restrict__ out) {
  __shared__ float s_msg[NE];   // c2v planes, 96 KB
  __shared__ float s_vl[NV];    // var LLR plane, 32 KB

  const int tid = threadIdx.x;
  const int b = blockIdx.x;
  const float* chrow = ch + (size_t)b * NV;
  const float4* ch4 = (const float4*)chrow;

  float4 chreg[2];
  chreg[0] = ch4[tid];           // vars 4*tid .. 4*tid+3
  chreg[1] = ch4[1024 + tid];    // vars 4096+4*tid ..

  float w[NITER];
#pragma unroll
  for (int i = 0; i < NITER; ++i) w[i] = wts[i];

  // Preload slot indices (writes) and masked var indices (vl reads).
  int idx[4][6];
  int vidx[4][6];
#pragma unroll
  for (int r = 0; r < 4; ++r) {
    int c = tid + r * 1024;
    unsigned int p0 = slotp[c];
    unsigned int p1 = slotp[NC + c];
    unsigned int p2 = slotp[2 * NC + c];
    idx[r][0] = (int)(p0 & 0xFFFFu); idx[r][1] = (int)(p0 >> 16);
    idx[r][2] = (int)(p1 & 0xFFFFu); idx[r][3] = (int)(p1 >> 16);
    idx[r][4] = (int)(p2 & 0xFFFFu); idx[r][5] = (int)(p2 >> 16);
#pragma unroll
    for (int j = 0; j < 6; ++j) vidx[r][j] = idx[r][j] & (NV - 1);
  }

  // c2v for this thread's 4 checks, resident in registers across iterations.
  float creg[4][6];
#pragma unroll
  for (int r = 0; r < 4; ++r)
#pragma unroll
    for (int j = 0; j < 6; ++j) creg[r][j] = 0.0f;

  float4* m0 = (float4*)&s_msg[0];
  float4* m1 = (float4*)&s_msg[NV];
  float4* m2 = (float4*)&s_msg[2 * NV];
  float4* vl4 = (float4*)s_vl;

  // ---- init: vl = ch (it0 v2c = vl - 0 = ch) ------------------------------
#pragma unroll
  for (int p = 0; p < 2; ++p) vl4[p * 1024 + tid] = chreg[p];
  __syncthreads();

  for (int it = 0; it < NITER; ++it) {
    const float wi = w[it];

    // ---- Phase B: hoist ALL 24 vl reads (independent, pipelined) ----------
    float tv[4][6];
#pragma unroll
    for (int r = 0; r < 4; ++r)
#pragma unroll
      for (int j = 0; j < 6; ++j) tv[r][j] = s_vl[vidx[r][j]];

    // ---- Phase B compute + writes -----------------------------------------
#pragma unroll
    for (int r = 0; r < 4; ++r) {
      unsigned int u[6];
      float av[6];
      unsigned int xs = 0u;
#pragma unroll
      for (int j = 0; j < 6; ++j) {
        float t = tv[r][j] - creg[r][j];
        unsigned int uu = __float_as_uint(t);
        u[j] = uu;
        xs ^= uu;
        av[j] = __uint_as_float(uu & 0x7FFFFFFFu);
      }
      // 2-min tree: exact, order-independent (min3/med3/max)
      float m1a = fminf(fminf(av[0], av[1]), av[2]);
      float m1b = fminf(fminf(av[3], av[4]), av[5]);
      float meda = __builtin_amdgcn_fmed3f(av[0], av[1], av[2]);
      float medb = __builtin_amdgcn_fmed3f(av[3], av[4], av[5]);
      float m1v = fminf(m1a, m1b);
      float m2v = fminf(fminf(meda, medb), fmaxf(m1a, m1b));
      const bool anyz = (m1v == 0.0f);
      const float m1w = m1v * wi;
      const float m2w = m2v * wi;
#pragma unroll
      for (int j = 0; j < 6; ++j) {
        float mag = (av[j] == m1v) ? m2w : m1w;  // ties: m2v==m1v, matches ref
        unsigned int s = (xs ^ u[j]) & 0x80000000u;
        float o = __uint_as_float(__float_as_uint(mag) ^ s);
        if (anyz) o = 0.0f;
        creg[r][j] = o;
        s_msg[idx[r][j]] = o;
      }
    }
    __syncthreads();

    // ---- Phase A: vl = ch + ((c0+c1)+c2), one wide write ------------------
    if (it < NITER - 1) {
#pragma unroll
      for (int p = 0; p < 2; ++p) {
        int i4 = p * 1024 + tid;
        float4 c0 = m0[i4], c1 = m1[i4], c2 = m2[i4];
        float4 cr = chreg[p];
        float4 vl;
        vl.x = cr.x + ((c0.x + c1.x) + c2.x);   // np.add.at association
        vl.y = cr.y + ((c0.y + c1.y) + c2.y);
        vl.z = cr.z + ((c0.z + c1.z) + c2.z);
        vl.w = cr.w + ((c0.w + c1.w) + c2.w);
        vl4[i4] = vl;
      }
      __syncthreads();
    }
  }

  // ---- Final: out = ch + ((c0+c1)+c2), float4 stores ----------------------
  float4* orow4 = (float4*)(out + (size_t)b * NV);
#pragma unroll
  for (int p = 0; p < 2; ++p) {
    int i4 = p * 1024 + tid;
    float4 c0 = m0[i4], c1 = m1[i4], c2 = m2[i4];
    float4 cr = chreg[p];
    float4 o;
    o.x = cr.x + ((c0.x + c1.x) + c2.x);
    o.y = cr.y + ((c0.y + c1.y) + c2.y);
    o.z = cr.z + ((c0.z + c1.z) + c2.z);
    o.w = cr.w + ((c0.w + c1.w) + c2.w);
    orow4[i4] = o;
  }
}

// ---------------------------------------------------------------------------

extern "C" void kernel_launch(void* const* d_in, const int* in_sizes, int n_in,
                              void* d_out, int out_size, void* d_ws, size_t ws_size,
                              hipStream_t stream) {
  (void)in_sizes; (void)n_in; (void)out_size; (void)ws_size;

  const float* ch   = (const float*)d_in[0];   // [BATCH, NV] f32
  const float* wts  = (const float*)d_in[1];   // [NITER, 1] f32
  const int*  Hcols = (const int*)d_in[3];     // [NE] i32
  float* out = (float*)d_out;

  char* ws = (char*)d_ws;
  unsigned short* cslot = (unsigned short*)(ws + 0);      // 49152 B
  unsigned int*   slotp = (unsigned int*)(ws + 49152);    // 49152 B
  // total ws use: 98304 B

  build_all<<<1, 1024, 0, stream>>>(Hcols, cslot);
  greedy_schedule<<<NC / 64, 64, 0, stream>>>(cslot, slotp);

  decode_kernel<<<BATCH, 1024, 0, stream>>>(ch, wts, slotp, out);
}

// Round 16
// 136.089 us; speedup vs baseline: 3.4563x; 1.0819x over previous
//
#include <hip/hip_runtime.h>
#include <stdint.h>

// Problem constants (fixed by the reference)
#define NV    8192   // variables
#define NC    4096   // checks
#define DC    6      // edges per check
#define DV    3      // edges per variable
#define NE    24576  // edges
#define NITER 5
#define BATCH 2048

// ---------------------------------------------------------------------------
// Setup 1: per-var edge lists (atomic order; ranks are derived order-
// independently downstream, so atomic arbitration never affects d_out).
// ---------------------------------------------------------------------------

__global__ void build_v2e(const int* __restrict__ cols, int* __restrict__ cnt,
                          unsigned short* __restrict__ v2e_tmp) {
  int e = blockIdx.x * blockDim.x + threadIdx.x;
  if (e >= NE) return;
  int v = cols[e];
  int s = atomicAdd(&cnt[v], 1);
  v2e_tmp[v * DV + s] = (unsigned short)e;
}

// ---------------------------------------------------------------------------
// Setup 2 (fused invert + schedule): QUARTER-granular greedy bank schedule
// (R8-verbatim auction; ties the exact Kempe coloring within the
// unschedulable conflict floor — R14 measured −0.2e7 counter, ±0 us time).
// Fused in: each lane computes its check's 6 slot codes directly:
//   slot(e) = rank*NV + var(e), rank = #{var's edges < e}  (== sorted rank,
//   independent of v2e_tmp's atomic ordering -> deterministic).
// Lanes of the same 16-lane quarter hitting the same bank serialize;
// objective per row j and quarter q: <=1 lane per bank (bank = var & 31).
// Any per-check edge permutation is BIT-EXACT for the decoder (check update
// is order-symmetric), so scheduler races never affect d_out.
// ---------------------------------------------------------------------------

__device__ __forceinline__ int qc(int n) { return (n > 1) ? (n - 1) : 0; }

__global__ __launch_bounds__(64) void greedy_schedule(
    const int* __restrict__ cols, const unsigned short* __restrict__ v2e_tmp,
    unsigned int* __restrict__ slotp) {
  __shared__ unsigned short sl[64][6];
  __shared__ unsigned char perm[64][6];
  __shared__ int qhist[4][32];    // quarter, bank: candidate contention
  __shared__ int cnt[6][4][32];   // row, quarter, bank

  const int l = threadIdx.x;
  const int q = l >> 4;
  const int c = blockIdx.x * 64 + l;

  // ---- fused invert_slots: slot codes for this check's 6 edges ------------
  int bank[6];
#pragma unroll
  for (int k = 0; k < 6; ++k) {
    int e = c * 6 + k;
    int v = cols[e];
    int t0 = v2e_tmp[v * 3 + 0];
    int t1 = v2e_tmp[v * 3 + 1];
    int t2 = v2e_tmp[v * 3 + 2];
    int rank = (t0 < e) + (t1 < e) + (t2 < e);
    sl[l][k] = (unsigned short)(rank * NV + v);
    bank[k] = v & 31;               // NV % 32 == 0 -> bank = var & 31
  }

  for (int t = l; t < 128; t += 64) ((int*)qhist)[t] = 0;
  for (int t = l; t < 768; t += 64) ((int*)cnt)[t] = 0;
  __syncthreads();

#pragma unroll
  for (int k = 0; k < 6; ++k) atomicAdd(&qhist[q][bank[k]], 1);
  __syncthreads();

  // ---- per-lane candidate order: contention descending (15-CE network) ----
  int key[6];
#pragma unroll
  for (int k = 0; k < 6; ++k) key[k] = (qhist[q][bank[k]] << 3) | k;
#pragma unroll
  for (int i = 0; i < 5; ++i) {
#pragma unroll
    for (int j2 = 0; j2 < 5 - i; ++j2) {
      if (key[j2] < key[j2 + 1]) {
        int t = key[j2]; key[j2] = key[j2 + 1]; key[j2 + 1] = t;
      }
    }
  }

  // ---- Stage 1: hardest-first strict auction, relaxed fallback ------------
  unsigned int used = 0;
  for (int j = 0; j < 6; ++j) {
    int placed = -1;
    for (int s = 0; s < 6; ++s) {
      int k = key[s] & 7;
      if (used & (1u << k)) continue;
      int bk = bank[k];
      if (cnt[j][q][bk] == 0) {
        if (atomicAdd(&cnt[j][q][bk], 1) == 0) { placed = k; break; }
        atomicSub(&cnt[j][q][bk], 1);
      }
    }
    if (placed < 0) {                    // relaxed: min-count unused candidate
      int bc = 1 << 30;
      for (int k = 0; k < 6; ++k) {
        if (used & (1u << k)) continue;
        int cc = cnt[j][q][bank[k]];
        if (cc < bc) { bc = cc; placed = k; }
      }
      atomicAdd(&cnt[j][q][bank[placed]], 1);
    }
    used |= (1u << placed);
    perm[l][j] = (unsigned char)placed;
    __syncthreads();
  }

  // ---- Stage 2: ONE quarter-cost swap-improvement pass --------------------
  for (int j1 = 0; j1 < 6; ++j1) {
    for (int j2 = j1 + 1; j2 < 6; ++j2) {
      int k1 = perm[l][j1], k2 = perm[l][j2];
      int b1 = bank[k1], b2 = bank[k2];
      if (b1 != b2) {
        int c11 = cnt[j1][q][b1], c12 = cnt[j1][q][b2];
        int c21 = cnt[j2][q][b1], c22 = cnt[j2][q][b2];
        int dOld = qc(c11) + qc(c12) + qc(c21) + qc(c22);
        int dNew = qc(c11 - 1) + qc(c12 + 1) + qc(c21 + 1) + qc(c22 - 1);
        if (dNew < dOld) {
          atomicSub(&cnt[j1][q][b1], 1); atomicAdd(&cnt[j1][q][b2], 1);
          atomicSub(&cnt[j2][q][b2], 1); atomicAdd(&cnt[j2][q][b1], 1);
          perm[l][j1] = (unsigned char)k2; perm[l][j2] = (unsigned char)k1;
        }
      }
      __syncthreads();
    }
  }

  unsigned short pm[6];
#pragma unroll
  for (int j = 0; j < 6; ++j) pm[j] = sl[l][perm[l][j]];
  slotp[0 * NC + c] = (unsigned int)pm[0] | ((unsigned int)pm[1] << 16);
  slotp[1 * NC + c] = (unsigned int)pm[2] | ((unsigned int)pm[3] << 16);
  slotp[2 * NC + c] = (unsigned int)pm[4] | ((unsigned int)pm[5] << 16);
}

// ---------------------------------------------------------------------------
// Fused decoder (R10-verbatim): one workgroup per batch element.
// LDS: 3 c2v planes (var-major, 96 KB) + 1 vl plane (32 KB) = 128 KB.
// c2v lives in the owning check-thread's REGISTERS across iterations.
// ---------------------------------------------------------------------------

__global__ __launch_bounds__(1024, 4) void decode_kernel(
    const float* __restrict__ ch, const float* __restrict__ wts,
    const unsigned int* __restrict__ slotp, float* __restrict__ out) {
  __shared__ float s_msg[NE];   // c2v planes, 96 KB
  __shared__ float s_vl[NV];    // var LLR plane, 32 KB

  const int tid = threadIdx.x;
  const int b = blockIdx.x;
  const float* chrow = ch + (size_t)b * NV;
  const float4* ch4 = (const float4*)chrow;

  float4 chreg[2];
  chreg[0] = ch4[tid];           // vars 4*tid .. 4*tid+3
  chreg[1] = ch4[1024 + tid];    // vars 4096+4*tid ..

  float w[NITER];
#pragma unroll
  for (int i = 0; i < NITER; ++i) w[i] = wts[i];

  // Preload slot indices (writes) and masked var indices (vl reads).
  int idx[4][6];
  int vidx[4][6];
#pragma unroll
  for (int r = 0; r < 4; ++r) {
    int c = tid + r * 1024;
    unsigned int p0 = slotp[c];
    unsigned int p1 = slotp[NC + c];
    unsigned int p2 = slotp[2 * NC + c];
    idx[r][0] = (int)(p0 & 0xFFFFu); idx[r][1] = (int)(p0 >> 16);
    idx[r][2] = (int)(p1 & 0xFFFFu); idx[r][3] = (int)(p1 >> 16);
    idx[r][4] = (int)(p2 & 0xFFFFu); idx[r][5] = (int)(p2 >> 16);
#pragma unroll
    for (int j = 0; j < 6; ++j) vidx[r][j] = idx[r][j] & (NV - 1);
  }

  // c2v for this thread's 4 checks, resident in registers across iterations.
  float creg[4][6];
#pragma unroll
  for (int r = 0; r < 4; ++r)
#pragma unroll
    for (int j = 0; j < 6; ++j) creg[r][j] = 0.0f;

  float4* m0 = (float4*)&s_msg[0];
  float4* m1 = (float4*)&s_msg[NV];
  float4* m2 = (float4*)&s_msg[2 * NV];
  float4* vl4 = (float4*)s_vl;

  // ---- init: vl = ch (it0 v2c = vl - 0 = ch) ------------------------------
#pragma unroll
  for (int p = 0; p < 2; ++p) vl4[p * 1024 + tid] = chreg[p];
  __syncthreads();

  for (int it = 0; it < NITER; ++it) {
    const float wi = w[it];

    // ---- Phase B: hoist ALL 24 vl reads (independent, pipelined) ----------
    float tv[4][6];
#pragma unroll
    for (int r = 0; r < 4; ++r)
#pragma unroll
      for (int j = 0; j < 6; ++j) tv[r][j] = s_vl[vidx[r][j]];

    // ---- Phase B compute + writes -----------------------------------------
#pragma unroll
    for (int r = 0; r < 4; ++r) {
      unsigned int u[6];
      float av[6];
      unsigned int xs = 0u;
#pragma unroll
      for (int j = 0; j < 6; ++j) {
        float t = tv[r][j] - creg[r][j];
        unsigned int uu = __float_as_uint(t);
        u[j] = uu;
        xs ^= uu;
        av[j] = __uint_as_float(uu & 0x7FFFFFFFu);
      }
      // 2-min tree: exact, order-independent (min3/med3/max)
      float m1a = fminf(fminf(av[0], av[1]), av[2]);
      float m1b = fminf(fminf(av[3], av[4]), av[5]);
      float meda = __builtin_amdgcn_fmed3f(av[0], av[1], av[2]);
      float medb = __builtin_amdgcn_fmed3f(av[3], av[4], av[5]);
      float m1v = fminf(m1a, m1b);
      float m2v = fminf(fminf(meda, medb), fmaxf(m1a, m1b));
      const bool anyz = (m1v == 0.0f);
      const float m1w = m1v * wi;
      const float m2w = m2v * wi;
#pragma unroll
      for (int j = 0; j < 6; ++j) {
        float mag = (av[j] == m1v) ? m2w : m1w;  // ties: m2v==m1v, matches ref
        unsigned int s = (xs ^ u[j]) & 0x80000000u;
        float o = __uint_as_float(__float_as_uint(mag) ^ s);
        if (anyz) o = 0.0f;
        creg[r][j] = o;
        s_msg[idx[r][j]] = o;
      }
    }
    __syncthreads();

    // ---- Phase A: vl = ch + ((c0+c1)+c2), one wide write ------------------
    if (it < NITER - 1) {
#pragma unroll
      for (int p = 0; p < 2; ++p) {
        int i4 = p * 1024 + tid;
        float4 c0 = m0[i4], c1 = m1[i4], c2 = m2[i4];
        float4 cr = chreg[p];
        float4 vl;
        vl.x = cr.x + ((c0.x + c1.x) + c2.x);   // np.add.at association
        vl.y = cr.y + ((c0.y + c1.y) + c2.y);
        vl.z = cr.z + ((c0.z + c1.z) + c2.z);
        vl.w = cr.w + ((c0.w + c1.w) + c2.w);
        vl4[i4] = vl;
      }
      __syncthreads();
    }
  }

  // ---- Final: out = ch + ((c0+c1)+c2), float4 stores ----------------------
  float4* orow4 = (float4*)(out + (size_t)b * NV);
#pragma unroll
  for (int p = 0; p < 2; ++p) {
    int i4 = p * 1024 + tid;
    float4 c0 = m0[i4], c1 = m1[i4], c2 = m2[i4];
    float4 cr = chreg[p];
    float4 o;
    o.x = cr.x + ((c0.x + c1.x) + c2.x);
    o.y = cr.y + ((c0.y + c1.y) + c2.y);
    o.z = cr.z + ((c0.z + c1.z) + c2.z);
    o.w = cr.w + ((c0.w + c1.w) + c2.w);
    orow4[i4] = o;
  }
}

// ---------------------------------------------------------------------------

extern "C" void kernel_launch(void* const* d_in, const int* in_sizes, int n_in,
                              void* d_out, int out_size, void* d_ws, size_t ws_size,
                              hipStream_t stream) {
  (void)in_sizes; (void)n_in; (void)out_size; (void)ws_size;

  const float* ch   = (const float*)d_in[0];   // [BATCH, NV] f32
  const float* wts  = (const float*)d_in[1];   // [NITER, 1] f32
  const int*  Hcols = (const int*)d_in[3];     // [NE] i32
  float* out = (float*)d_out;

  char* ws = (char*)d_ws;
  int*            cnt     = (int*)(ws + 0);                  // 32768 B
  unsigned short* v2e_tmp = (unsigned short*)(ws + 32768);   // 49152 B
  unsigned int*   slotp   = (unsigned int*)(ws + 81920);     // 49152 B
  // total ws use: 131072 B

  hipMemsetAsync(cnt, 0, NV * sizeof(int), stream);
  build_v2e<<<(NE + 255) / 256, 256, 0, stream>>>(Hcols, cnt, v2e_tmp);
  greedy_schedule<<<NC / 64, 64, 0, stream>>>(Hcols, v2e_tmp, slotp);

  decode_kernel<<<BATCH, 1024, 0, stream>>>(ch, wts, slotp, out);
}